// Round 6
// baseline (529.218 us; speedup 1.0000x reference)
//
#include <hip/hip_runtime.h>
#include <hip/hip_cooperative_groups.h>
#include <math.h>

namespace cg = cooperative_groups;

#define BB 8
#define NN 256
#define DD 512
#define HH 16
#define KK 4
#define DKK 32
#define FFN_ 2048
#define NEGV -1e12f

typedef __attribute__((ext_vector_type(8))) short bf16x8;
typedef __attribute__((ext_vector_type(4))) float f32x4;

__device__ __forceinline__ unsigned short f2bf(float f) {
    union { float f; unsigned int u; } v; v.f = f;
    unsigned int r = (v.u + 0x7FFFu + ((v.u >> 16) & 1u)) >> 16;
    return (unsigned short)r;
}
__device__ __forceinline__ float bf2f(unsigned short u) {
    union { unsigned int i; float f; } v; v.i = ((unsigned int)u) << 16;
    return v.f;
}
__device__ __forceinline__ void gload_lds16(const unsigned short* g, unsigned short* l) {
    __builtin_amdgcn_global_load_lds(
        (const __attribute__((address_space(1))) void*)g,
        (__attribute__((address_space(3))) void*)l, 16, 0, 0);
}

// ---------------------------------------------------------------------------
// S0: prep. 5379 jobs over 256 blocks: 0..4095 weight transposes (32x32 tile,
// fp32 [K][N] -> bf16 [N][K]); 4096..4351 x->bf16; 4352..5375 biasMs
// (mask+dist folded into bf16 bias, NEG where disallowed); 5376..5378 bqkv.
// ---------------------------------------------------------------------------
__device__ void prep_stage(
    const float* __restrict__ x,
    const float* __restrict__ Wq, const float* __restrict__ Wk,
    const float* __restrict__ Wv, const float* __restrict__ W1,
    const float* __restrict__ W2, const float* __restrict__ Wf1,
    const float* __restrict__ Wf2,
    const float* __restrict__ bq, const float* __restrict__ bk,
    const float* __restrict__ bv,
    const float* __restrict__ attn_bias, const int* __restrict__ mask,
    const float* __restrict__ dist, const float* __restrict__ dist_bar,
    unsigned short* __restrict__ xb, unsigned short* __restrict__ Wqkvt,
    unsigned short* __restrict__ W1t, unsigned short* __restrict__ W2t,
    unsigned short* __restrict__ Wf1t, unsigned short* __restrict__ Wf2t,
    float* __restrict__ bqkv, unsigned short* __restrict__ biasMs, char* lds)
{
    float* tile = (float*)lds;  // [32][33] fp32 = 4224 B
    const int t = threadIdx.x;

    for (int job = blockIdx.x; job < 5379; job += 256) {
        if (job < 4096) {
            const float* src; unsigned short* dst; int Kd, Nd, ti;
            if (job < 768) {
                const int w = job >> 8; ti = job & 255;
                src = (w == 0) ? Wq : (w == 1) ? Wk : Wv;
                dst = Wqkvt + w * 262144; Kd = 512; Nd = 512;
            } else if (job < 1792) { src = W1;  dst = W1t;  Kd = 2048; Nd = 512;  ti = job - 768; }
            else if (job < 2048)   { src = W2;  dst = W2t;  Kd = 512;  Nd = 512;  ti = job - 1792; }
            else if (job < 3072)   { src = Wf1; dst = Wf1t; Kd = 512;  Nd = 2048; ti = job - 2048; }
            else                   { src = Wf2; dst = Wf2t; Kd = 2048; Nd = 512;  ti = job - 3072; }
            const int kt = Kd >> 5;
            const int k0 = (ti % kt) * 32, n0 = (ti / kt) * 32;
            const int xx = t & 31, yy = t >> 5;  // 32 x 16, 2 rows each
            __syncthreads();
            #pragma unroll
            for (int rr = 0; rr < 2; ++rr)
                tile[(yy * 2 + rr) * 33 + xx] = src[(size_t)(k0 + yy * 2 + rr) * Nd + n0 + xx];
            __syncthreads();
            #pragma unroll
            for (int rr = 0; rr < 2; ++rr)
                dst[(size_t)(n0 + yy * 2 + rr) * Kd + k0 + xx] = f2bf(tile[xx * 33 + yy * 2 + rr]);
        } else if (job < 4352) {
            const int j = job - 4096;
            const size_t i0 = (size_t)j * 4096 + t * 8;
            const float4 a = *(const float4*)(x + i0);
            const float4 c = *(const float4*)(x + i0 + 4);
            unsigned short o[8] = {f2bf(a.x), f2bf(a.y), f2bf(a.z), f2bf(a.w),
                                   f2bf(c.x), f2bf(c.y), f2bf(c.z), f2bf(c.w)};
            *(bf16x8*)(xb + i0) = *(bf16x8*)o;
        } else if (job < 5376) {
            const int j = job - 4352;
            const int b = j >> 7, ks = (j >> 5) & 3, rgp = j & 31;
            const int rg = rgp * 2 + (t >> 8), m = t & 255;
            const int bx = (b * 4 + ks) * 64 + rg;
            const float bar = dist_bar[ks];
            ushort4 o; unsigned short* po = (unsigned short*)&o;
            #pragma unroll
            for (int i = 0; i < 4; ++i) {
                const int n = rg * 4 + i;
                const int mk = mask[((size_t)(b * NN) + n) * NN + m];
                bool allowed = (n == 0) || (m == 0);
                if (!allowed)
                    allowed = dist[((size_t)(b * 255) + (n - 1)) * 255 + (m - 1)] < bar;
                const float bias = attn_bias[(((size_t)(b * KK) + ks) * NN + n) * NN + m];
                po[i] = f2bf((mk != 0 && allowed) ? bias : NEGV);
            }
            *(ushort4*)(biasMs + (size_t)bx * 1024 + m * 4) = o;
        } else {
            const int j = job - 5376;
            const int i = j * 512 + t;
            bqkv[i] = (i < 512) ? bq[i] : (i < 1024) ? bk[i - 512] : bv[i - 1024];
        }
    }
}

// ---------------------------------------------------------------------------
// 128x128 MFMA GEMM stage, 8 waves (4m x 2n, wave = 32x64), BK=64.
// QKV=1: split epilogue (col<1024 -> qkvb pitch 1536; else vT transposed).
// QKV=0: bf16 out pitch N with ACT (2=gelu).
// ---------------------------------------------------------------------------
template<int ACT, int QKV>
__device__ void gemm128(const unsigned short* __restrict__ A,
                        const unsigned short* __restrict__ Bt,
                        const float* __restrict__ bias,
                        unsigned short* __restrict__ Cb,
                        unsigned short* __restrict__ vTo,
                        int N, int Kdim, int njobs, int ntile, char* lds)
{
    unsigned short* As = (unsigned short*)lds;      // 128*64
    unsigned short* Bs = As + 8192;
    const int t = threadIdx.x, lane = t & 63, wv = t >> 6;
    const int wm = wv >> 1, wn = wv & 1;
    const int L = lane & 15, qd = lane >> 4;
    const int job = blockIdx.x;
    if (job >= njobs) return;
    const int n0 = (job % ntile) * 128, m0 = (job / ntile) * 128;

    f32x4 acc[2][4];
    #pragma unroll
    for (int i = 0; i < 2; ++i)
        #pragma unroll
        for (int j = 0; j < 4; ++j) acc[i][j] = (f32x4){0.f, 0.f, 0.f, 0.f};

    for (int kt = 0; kt < Kdim; kt += 64) {
        #pragma unroll
        for (int i = 0; i < 2; ++i) {
            gload_lds16(A  + (size_t)(m0 + wv * 16 + i * 8 + (lane >> 3)) * Kdim + kt + (lane & 7) * 8,
                        As + (wv * 16 + i * 8) * 64);
            gload_lds16(Bt + (size_t)(n0 + wv * 16 + i * 8 + (lane >> 3)) * Kdim + kt + (lane & 7) * 8,
                        Bs + (wv * 16 + i * 8) * 64);
        }
        __syncthreads();
        #pragma unroll
        for (int s = 0; s < 2; ++s) {
            bf16x8 af[2], bfb[4];
            #pragma unroll
            for (int i = 0; i < 2; ++i)
                af[i] = *(const bf16x8*)(As + (wm * 32 + i * 16 + L) * 64 + s * 32 + qd * 8);
            #pragma unroll
            for (int j = 0; j < 4; ++j)
                bfb[j] = *(const bf16x8*)(Bs + (wn * 64 + j * 16 + L) * 64 + s * 32 + qd * 8);
            #pragma unroll
            for (int i = 0; i < 2; ++i)
                #pragma unroll
                for (int j = 0; j < 4; ++j)
                    acc[i][j] = __builtin_amdgcn_mfma_f32_16x16x32_bf16(af[i], bfb[j], acc[i][j], 0, 0, 0);
        }
        __syncthreads();
    }

    #pragma unroll
    for (int j = 0; j < 4; ++j) {
        const int col = n0 + wn * 64 + j * 16 + L;
        const float bv = bias[col];
        #pragma unroll
        for (int i = 0; i < 2; ++i) {
            const int rowb = m0 + wm * 32 + i * 16 + qd * 4;
            if (QKV == 1 && col >= 1024) {
                ushort4 pk; unsigned short* pp = (unsigned short*)&pk;
                #pragma unroll
                for (int r = 0; r < 4; ++r) pp[r] = f2bf(acc[i][j][r] + bv);
                *(ushort4*)(vTo + (size_t)(col - 1024) * 2048 + rowb) = pk;
            } else {
                #pragma unroll
                for (int r = 0; r < 4; ++r) {
                    float v = acc[i][j][r] + bv;
                    if (ACT == 2) v = 0.5f * v * (1.0f + erff(v * 0.70710678118654752f));
                    Cb[(size_t)(rowb + r) * N + col] = f2bf(v);
                }
            }
        }
    }
}

// ---------------------------------------------------------------------------
// 64x64 MFMA GEMM stage, 8 waves (4m x 2n, wave = 16x32), BK=64, 256 jobs.
// ACT 1 = silu. OUTF32: fp32 out (pitch N) else bf16.
// ---------------------------------------------------------------------------
template<int ACT, int OUTF32>
__device__ void gemm64(const unsigned short* __restrict__ A,
                       const unsigned short* __restrict__ Bt,
                       const float* __restrict__ bias,
                       unsigned short* __restrict__ Cb, float* __restrict__ Cf,
                       int N, int Kdim, char* lds)
{
    unsigned short* As = (unsigned short*)lds;      // 64*64
    unsigned short* Bs = As + 4096;
    const int t = threadIdx.x, lane = t & 63, wv = t >> 6;
    const int wm = wv >> 1, wn = wv & 1;
    const int L = lane & 15, qd = lane >> 4;
    const int ntile = N >> 6;
    const int job = blockIdx.x;
    const int n0 = (job & (ntile - 1)) * 64, m0 = (job / ntile) * 64;

    f32x4 acc[2] = {(f32x4){0.f,0.f,0.f,0.f}, (f32x4){0.f,0.f,0.f,0.f}};

    for (int kt = 0; kt < Kdim; kt += 64) {
        gload_lds16(A  + (size_t)(m0 + wv * 8 + (lane >> 3)) * Kdim + kt + (lane & 7) * 8,
                    As + wv * 8 * 64);
        gload_lds16(Bt + (size_t)(n0 + wv * 8 + (lane >> 3)) * Kdim + kt + (lane & 7) * 8,
                    Bs + wv * 8 * 64);
        __syncthreads();
        #pragma unroll
        for (int s = 0; s < 2; ++s) {
            const bf16x8 a = *(const bf16x8*)(As + (wm * 16 + L) * 64 + s * 32 + qd * 8);
            #pragma unroll
            for (int j = 0; j < 2; ++j) {
                const bf16x8 b = *(const bf16x8*)(Bs + (wn * 32 + j * 16 + L) * 64 + s * 32 + qd * 8);
                acc[j] = __builtin_amdgcn_mfma_f32_16x16x32_bf16(a, b, acc[j], 0, 0, 0);
            }
        }
        __syncthreads();
    }

    #pragma unroll
    for (int j = 0; j < 2; ++j) {
        const int col = n0 + wn * 32 + j * 16 + L;
        const float bv = bias[col];
        #pragma unroll
        for (int r = 0; r < 4; ++r) {
            const int row = m0 + wm * 16 + qd * 4 + r;
            float v = acc[j][r] + bv;
            if (ACT == 1) v = v / (1.0f + __expf(-v));
            if (OUTF32) Cf[(size_t)row * N + col] = v;
            else        Cb[(size_t)row * N + col] = f2bf(v);
        }
    }
}

// ---------------------------------------------------------------------------
// Attention stage: 256 blocks = (b, h, qhalf); 8 waves, wave = 16 queries.
// Q/K/bias fragments straight from global (L2-hot); V^T block-staged in LDS;
// P via wave-private 32-key LDS chunks (no barriers after staging).
// ---------------------------------------------------------------------------
__device__ void attn_stage(const unsigned short* __restrict__ qkvb,
                           const unsigned short* __restrict__ vTb,
                           const unsigned short* __restrict__ biasMs,
                           unsigned short* __restrict__ msgT, char* lds)
{
    const int bid = blockIdx.x;
    const int b = bid >> 5, h = (bid >> 1) & 15, qh = bid & 1;
    const int t = threadIdx.x, lane = t & 63, wv = t >> 6;
    const int L = lane & 15, qd = lane >> 4;
    const int qbase = qh * 128 + wv * 16;

    unsigned short* Vs  = (unsigned short*)lds;                        // 32 x 264
    unsigned short* Pch = (unsigned short*)(lds + 16896) + wv * 640;   // 16 x 40 / wave
    unsigned short* Ot  = (unsigned short*)(lds + 27136) + wv * 768;   // 32 x 24 / wave

    {   // stage V^T [32 d][256 m] pitch 264; each thread covers 16 ushorts
        // (R5 BUG was here: only the low 8 of each 16-stride segment were
        //  written, leaving stale LDS garbage in the odd chunks -> NaN.)
        const int d = t >> 4, seg = t & 15;
        const unsigned short* gv = vTb + (size_t)(h * DKK + d) * 2048 + b * NN + seg * 16;
        *(bf16x8*)(Vs + d * 264 + seg * 16)     = *(const bf16x8*)(gv);
        *(bf16x8*)(Vs + d * 264 + seg * 16 + 8) = *(const bf16x8*)(gv + 8);
    }
    __syncthreads();

    // QK^T: operands per-lane from global
    f32x4 S[16];
    #pragma unroll
    for (int j = 0; j < 16; ++j) S[j] = (f32x4){0.f, 0.f, 0.f, 0.f};
    {
        const bf16x8 aq = *(const bf16x8*)(qkvb + (size_t)(b * NN + qbase + L) * 1536 + h * DKK + qd * 8);
        #pragma unroll
        for (int j = 0; j < 16; ++j) {
            const bf16x8 bk = *(const bf16x8*)(qkvb + (size_t)(b * NN + j * 16 + L) * 1536 + 512 + h * DKK + qd * 8);
            S[j] = __builtin_amdgcn_mfma_f32_16x16x32_bf16(aq, bk, S[j], 0, 0, 0);
        }
    }
    const float scale = 0.17677669529663687f;  // 1/sqrt(32)
    #pragma unroll
    for (int j = 0; j < 16; ++j)
        #pragma unroll
        for (int r = 0; r < 4; ++r) S[j][r] *= scale;
    const int rgb = qbase >> 2;

    for (int ks = 0; ks < KK; ++ks) {
        const unsigned short* bp = biasMs + ((size_t)((b * KK + ks) * 64 + rgb + qd)) * 1024;

        ushort4 b4[16];
        float mx[4] = {-3e38f, -3e38f, -3e38f, -3e38f};
        #pragma unroll
        for (int j = 0; j < 16; ++j) {
            b4[j] = *(const ushort4*)(bp + (j * 16 + L) * 4);
            const unsigned short* pb = (const unsigned short*)&b4[j];
            #pragma unroll
            for (int r = 0; r < 4; ++r)
                mx[r] = fmaxf(mx[r], S[j][r] + bf2f(pb[r]));
        }
        #pragma unroll
        for (int off = 8; off > 0; off >>= 1)
            #pragma unroll
            for (int r = 0; r < 4; ++r) mx[r] = fmaxf(mx[r], __shfl_xor(mx[r], off));

        ushort4 e16[16];
        float sm[4] = {0.f, 0.f, 0.f, 0.f};
        #pragma unroll
        for (int j = 0; j < 16; ++j) {
            const unsigned short* pb = (const unsigned short*)&b4[j];
            unsigned short* pe = (unsigned short*)&e16[j];
            #pragma unroll
            for (int r = 0; r < 4; ++r) {
                const float e = __expf(S[j][r] + bf2f(pb[r]) - mx[r]);
                sm[r] += e;
                pe[r] = f2bf(e);
            }
        }
        #pragma unroll
        for (int off = 8; off > 0; off >>= 1)
            #pragma unroll
            for (int r = 0; r < 4; ++r) sm[r] += __shfl_xor(sm[r], off);
        float inv[4];
        #pragma unroll
        for (int r = 0; r < 4; ++r) inv[r] = 1.0f / sm[r];

        // PV over 32-key chunks via wave-private LDS
        f32x4 O[2];
        O[0] = (f32x4){0.f, 0.f, 0.f, 0.f};
        O[1] = (f32x4){0.f, 0.f, 0.f, 0.f};
        #pragma unroll
        for (int kc = 0; kc < 8; ++kc) {
            #pragma unroll
            for (int j2 = 0; j2 < 2; ++j2) {
                const unsigned short* pe = (const unsigned short*)&e16[kc * 2 + j2];
                #pragma unroll
                for (int r = 0; r < 4; ++r)
                    Pch[(qd * 4 + r) * 40 + j2 * 16 + L] = pe[r];
            }
            asm volatile("s_waitcnt lgkmcnt(0)" ::: "memory");
            const bf16x8 ap = *(const bf16x8*)(Pch + L * 40 + qd * 8);
            #pragma unroll
            for (int jt = 0; jt < 2; ++jt) {
                const bf16x8 bv = *(const bf16x8*)(Vs + (jt * 16 + L) * 264 + kc * 32 + qd * 8);
                O[jt] = __builtin_amdgcn_mfma_f32_16x16x32_bf16(ap, bv, O[jt], 0, 0, 0);
            }
        }

        // transpose O via wave-private Ot, store coalesced strips
        #pragma unroll
        for (int jt = 0; jt < 2; ++jt)
            #pragma unroll
            for (int r = 0; r < 4; ++r)
                Ot[(jt * 16 + L) * 24 + qd * 4 + r] = f2bf(O[jt][r] * inv[r]);
        asm volatile("s_waitcnt lgkmcnt(0)" ::: "memory");
        {
            const int d = lane >> 1, qp = lane & 1;
            const bf16x8 ov = *(const bf16x8*)(Ot + d * 24 + qp * 8);
            *(bf16x8*)(msgT + (size_t)b * 524288 +
                       ((size_t)((ks * HH + h) * DKK + d)) * 256 + qbase + qp * 8) = ov;
        }
    }
}

// ---------------------------------------------------------------------------
// Per-wave LayerNorm: row = bid*8 + wave; out = LN(a + r)*g + be.
// ---------------------------------------------------------------------------
template<int OUT16>
__device__ void ln_stage(const float* __restrict__ a, const float* __restrict__ r,
                         const float* __restrict__ g, const float* __restrict__ be,
                         float* __restrict__ out, unsigned short* __restrict__ outb)
{
    const int t = threadIdx.x, lane = t & 63, wv = t >> 6;
    const int row = blockIdx.x * 8 + wv;
    const size_t base = (size_t)row * DD + lane * 8;
    const int c0 = lane * 8;

    float z[8]; float s = 0.f;
    #pragma unroll
    for (int i = 0; i < 8; ++i) { z[i] = a[base + i] + r[base + i]; s += z[i]; }
    #pragma unroll
    for (int off = 32; off > 0; off >>= 1) s += __shfl_xor(s, off);
    const float mean = s * (1.0f / 512.0f);
    float v = 0.f;
    #pragma unroll
    for (int i = 0; i < 8; ++i) { z[i] -= mean; v += z[i] * z[i]; }
    #pragma unroll
    for (int off = 32; off > 0; off >>= 1) v += __shfl_xor(v, off);
    const float inv = rsqrtf(v * (1.0f / 512.0f) + 1e-6f);

    unsigned short o16[8];
    #pragma unroll
    for (int i = 0; i < 8; ++i) {
        const float o = z[i] * inv * g[c0 + i] + be[c0 + i];
        out[base + i] = o;
        if (OUT16) o16[i] = f2bf(o);
    }
    if (OUT16) *(bf16x8*)(outb + base) = *(bf16x8*)o16;
}

// ---------------------------------------------------------------------------
// The mega-kernel: whole block in one cooperative launch, 8 grid syncs.
// ---------------------------------------------------------------------------
__global__ __launch_bounds__(512, 2) void mega_kernel(
    const float* __restrict__ x, const float* __restrict__ dist,
    const float* __restrict__ dist_bar, const float* __restrict__ attn_bias,
    const int* __restrict__ mask,
    const float* __restrict__ Wq, const float* __restrict__ bq,
    const float* __restrict__ Wk, const float* __restrict__ bk,
    const float* __restrict__ Wv, const float* __restrict__ bv,
    const float* __restrict__ W1, const float* __restrict__ b1,
    const float* __restrict__ W2, const float* __restrict__ b2,
    const float* __restrict__ g1, const float* __restrict__ be1,
    const float* __restrict__ Wf1, const float* __restrict__ bf1,
    const float* __restrict__ Wf2, const float* __restrict__ bf2,
    const float* __restrict__ g2, const float* __restrict__ be2,
    float* __restrict__ ws, float* __restrict__ outp)
{
    __shared__ __align__(16) char smem[39424];
    cg::grid_group grid = cg::this_grid();

    // workspace map (float units)
    unsigned short* qkvb   = (unsigned short*)(ws + 0);          // [2048][1536] bf16
    unsigned short* vT     = (unsigned short*)(ws + 1572864);    // [512][2048] bf16
    unsigned short* xb     = (unsigned short*)(ws + 2097152);    // [2048][512] bf16
    unsigned short* msgT   = (unsigned short*)(ws + 2621440);    // [2048][2048] bf16 (scrambled)
    unsigned short* biasMs = (unsigned short*)(ws + 4718592);    // [2048][1024] bf16
    float*          bqkv   = ws + 5767168;                       // [1536] f32
    unsigned short* h1     = (unsigned short*)(ws + 5771264);    // [2048][512] bf16
    float*          h2     = ws + 6295552;                       // [2048][512] f32
    float*          yb     = ws + 7344128;                       // [2048][512] f32
    unsigned short* yb16   = (unsigned short*)(ws + 8392704);    // [2048][512] bf16
    unsigned short* g3     = (unsigned short*)(ws + 8916992);    // [2048][2048] bf16
    float*          fb     = ws + 11014144;                      // [2048][512] f32
    unsigned short* Wqkvt  = (unsigned short*)(ws + 12062720);   // [1536][512] bf16
    unsigned short* W1t    = (unsigned short*)(ws + 12455936);   // [512][2048] bf16
    unsigned short* W2t    = (unsigned short*)(ws + 12980224);   // [512][512] bf16
    unsigned short* Wf1t   = (unsigned short*)(ws + 13111296);   // [2048][512] bf16
    unsigned short* Wf2t   = (unsigned short*)(ws + 13635584);   // [512][2048] bf16

    // S0: prep
    prep_stage(x, Wq, Wk, Wv, W1, W2, Wf1, Wf2, bq, bk, bv,
               attn_bias, mask, dist, dist_bar,
               xb, Wqkvt, W1t, W2t, Wf1t, Wf2t, bqkv, biasMs, smem);
    grid.sync();
    // S1: QKV [2048,512]x[512,1536], v -> vT transposed
    gemm128<0, 1>(xb, Wqkvt, bqkv, qkvb, vT, 1536, DD, 192, 12, smem);
    grid.sync();
    // S2: 4-scale MFMA attention -> msgT (scrambled W1-input layout)
    attn_stage(qkvb, vT, biasMs, msgT, smem);
    grid.sync();
    // S3: h1 = silu(msgT @ W1 + b1)
    gemm64<1, 0>(msgT, W1t, b1, h1, nullptr, DD, 2048, smem);
    grid.sync();
    // S4: h2 = h1 @ W2 + b2 (fp32)
    gemm64<0, 1>(h1, W2t, b2, nullptr, h2, DD, DD, smem);
    grid.sync();
    // S5: y = LN(h2 + x)
    ln_stage<1>(h2, x, g1, be1, yb, yb16);
    grid.sync();
    // S6: g3 = gelu(y @ Wf1 + bf1)
    gemm128<2, 0>(yb16, Wf1t, bf1, g3, nullptr, FFN_, DD, 256, 16, smem);
    grid.sync();
    // S7: f = g3 @ Wf2 + bf2 (fp32)
    gemm64<0, 1>(g3, Wf2t, bf2, nullptr, fb, DD, 2048, smem);
    grid.sync();
    // S8: out = LN(f + y)
    ln_stage<0>(fb, yb, g2, be2, outp, nullptr);
}

// ---------------------------------------------------------------------------
extern "C" void kernel_launch(void* const* d_in, const int* in_sizes, int n_in,
                              void* d_out, int out_size, void* d_ws, size_t ws_size,
                              hipStream_t stream)
{
    const float* x         = (const float*)d_in[0];
    const float* dist      = (const float*)d_in[1];
    const float* dist_bar  = (const float*)d_in[2];
    const float* attn_bias = (const float*)d_in[3];
    const int*   mask      = (const int*)d_in[4];
    const float* Wq  = (const float*)d_in[6];  const float* bq  = (const float*)d_in[7];
    const float* Wk  = (const float*)d_in[8];  const float* bk  = (const float*)d_in[9];
    const float* Wv  = (const float*)d_in[10]; const float* bv  = (const float*)d_in[11];
    const float* W1  = (const float*)d_in[12]; const float* b1  = (const float*)d_in[13];
    const float* W2  = (const float*)d_in[14]; const float* b2  = (const float*)d_in[15];
    const float* g1  = (const float*)d_in[16]; const float* be1 = (const float*)d_in[17];
    const float* Wf1 = (const float*)d_in[18]; const float* bf1 = (const float*)d_in[19];
    const float* Wf2 = (const float*)d_in[20]; const float* bf2 = (const float*)d_in[21];
    const float* g2  = (const float*)d_in[22]; const float* be2 = (const float*)d_in[23];

    float* wsp  = (float*)d_ws;
    float* outp = (float*)d_out;

    void* kargs[] = {
        (void*)&x, (void*)&dist, (void*)&dist_bar, (void*)&attn_bias, (void*)&mask,
        (void*)&Wq, (void*)&bq, (void*)&Wk, (void*)&bk, (void*)&Wv, (void*)&bv,
        (void*)&W1, (void*)&b1, (void*)&W2, (void*)&b2, (void*)&g1, (void*)&be1,
        (void*)&Wf1, (void*)&bf1, (void*)&Wf2, (void*)&bf2, (void*)&g2, (void*)&be2,
        (void*)&wsp, (void*)&outp
    };
    hipLaunchCooperativeKernel((const void*)mega_kernel, dim3(256), dim3(512),
                               kargs, 0, stream);
}

// Round 7
// 283.475 us; speedup vs baseline: 1.8669x; 1.8669x over previous
//
#include <hip/hip_runtime.h>
#include <math.h>

#define BB 8
#define NN 256
#define DD 512
#define HH 16
#define KK 4
#define DKK 32
#define FFN_ 2048
#define NEGV -1e12f

typedef __attribute__((ext_vector_type(8))) short bf16x8;
typedef __attribute__((ext_vector_type(4))) float f32x4;

__device__ __forceinline__ unsigned short f2bf(float f) {
    union { float f; unsigned int u; } v; v.f = f;
    unsigned int r = (v.u + 0x7FFFu + ((v.u >> 16) & 1u)) >> 16;
    return (unsigned short)r;
}
__device__ __forceinline__ float bf2f(unsigned short u) {
    union { unsigned int i; float f; } v; v.i = ((unsigned int)u) << 16;
    return v.f;
}
__device__ __forceinline__ void gload_lds16(const unsigned short* g, unsigned short* l) {
    __builtin_amdgcn_global_load_lds(
        (const __attribute__((address_space(1))) void*)g,
        (__attribute__((address_space(3))) void*)l, 16, 0, 0);
}

// ---------------------------------------------------------------------------
// Merged prep (R4-proven): z=0..6 weight transposes fp32->bf16 Wt[N][K];
// z=7 x->bf16; z=8 bias concat; z=9 mask+dist+bias combine (biasMs).
// ---------------------------------------------------------------------------
__global__ __launch_bounds__(256) void prep_kernel(
    const float* __restrict__ x,
    const float* __restrict__ Wq, const float* __restrict__ Wk,
    const float* __restrict__ Wv, const float* __restrict__ W1,
    const float* __restrict__ W2, const float* __restrict__ Wf1,
    const float* __restrict__ Wf2,
    const float* __restrict__ bq, const float* __restrict__ bk,
    const float* __restrict__ bv,
    const float* __restrict__ attn_bias, const int* __restrict__ mask,
    const float* __restrict__ dist, const float* __restrict__ dist_bar,
    unsigned short* __restrict__ xb, unsigned short* __restrict__ Wqkvt,
    unsigned short* __restrict__ W1t, unsigned short* __restrict__ W2t,
    unsigned short* __restrict__ Wf1t, unsigned short* __restrict__ Wf2t,
    float* __restrict__ bqkv, unsigned short* __restrict__ biasMs)
{
    const int z = blockIdx.z;
    const int t = threadIdx.x;

    if (z == 7) {
        if (blockIdx.x >= 1024) return;
        const int i0 = blockIdx.x * 1024 + t * 4;
        float4 xv = *(const float4*)(x + i0);
        ushort4 o;
        o.x = f2bf(xv.x); o.y = f2bf(xv.y); o.z = f2bf(xv.z); o.w = f2bf(xv.w);
        *(ushort4*)(xb + i0) = o;
        return;
    }
    if (z == 8) {
        if (blockIdx.x >= 6) return;
        const int i = blockIdx.x * 256 + t;
        float v = (i < 512) ? bq[i] : (i < 1024) ? bk[i - 512] : bv[i - 1024];
        bqkv[i] = v;
        return;
    }
    if (z == 9) {
        const int bx = blockIdx.x;
        const int rg = bx & 63, ks = (bx >> 6) & 3, b = bx >> 8;
        const int m = t;
        const float bar = dist_bar[ks];
        ushort4 o; unsigned short* po = (unsigned short*)&o;
        #pragma unroll
        for (int i = 0; i < 4; ++i) {
            const int n = rg * 4 + i;
            const int mk = mask[((size_t)(b * NN) + n) * NN + m];
            bool allowed = (n == 0) || (m == 0);
            if (!allowed)
                allowed = dist[((size_t)(b * 255) + (n - 1)) * 255 + (m - 1)] < bar;
            const float bias = attn_bias[(((size_t)(b * KK) + ks) * NN + n) * NN + m];
            po[i] = f2bf((mk != 0 && allowed) ? bias : NEGV);
        }
        *(ushort4*)(biasMs + (size_t)bx * 1024 + m * 4) = o;
        return;
    }

    const float* src; unsigned short* dst; int Kd, Nd;
    switch (z) {
        case 0: src = Wq;  dst = Wqkvt;              Kd = 512;  Nd = 512;  break;
        case 1: src = Wk;  dst = Wqkvt + 512 * 512;  Kd = 512;  Nd = 512;  break;
        case 2: src = Wv;  dst = Wqkvt + 1024 * 512; Kd = 512;  Nd = 512;  break;
        case 3: src = W1;  dst = W1t;  Kd = 2048; Nd = 512;  break;
        case 4: src = W2;  dst = W2t;  Kd = 512;  Nd = 512;  break;
        case 5: src = Wf1; dst = Wf1t; Kd = 512;  Nd = 2048; break;
        default: src = Wf2; dst = Wf2t; Kd = 2048; Nd = 512; break;
    }
    const int ktiles = Kd / 32, ntiles = Nd / 32;
    const int ti = blockIdx.x;
    if (ti >= ktiles * ntiles) return;
    const int k0 = (ti % ktiles) * 32, n0 = (ti / ktiles) * 32;

    __shared__ float tile[32][33];
    const int xx = t & 31, yy = t >> 5;
    #pragma unroll
    for (int r = 0; r < 4; ++r)
        tile[yy * 4 + r][xx] = src[(size_t)(k0 + yy * 4 + r) * Nd + n0 + xx];
    __syncthreads();
    #pragma unroll
    for (int r = 0; r < 4; ++r)
        dst[(size_t)(n0 + yy * 4 + r) * Kd + k0 + xx] = f2bf(tile[xx][yy * 4 + r]);
}

// ---------------------------------------------------------------------------
// 512-thread 128x128 MFMA GEMM (R4-proven), 8 waves (4m x 2n), BK=64.
// EPI 0: bf16 out + ACT.  EPI 1: QKV split (col<1024 -> Cb pitch 1536, else
// vT transposed).
// ---------------------------------------------------------------------------
template<int ACT, int EPI>
__global__ __launch_bounds__(512) void mfma_gemm512(
    const unsigned short* __restrict__ A, const unsigned short* __restrict__ Bt,
    const float* __restrict__ bias, unsigned short* __restrict__ Cb,
    unsigned short* __restrict__ vT, int M, int N, int Kdim)
{
    __shared__ unsigned short As[128 * 64];
    __shared__ unsigned short Bs[128 * 64];

    const int t = threadIdx.x, lane = t & 63, wv = t >> 6;
    const int n0 = blockIdx.x * 128, m0 = blockIdx.y * 128;
    const int wm = wv >> 1, wn = wv & 1;
    const int L = lane & 15, qd = lane >> 4;
    const int sr = lane >> 3, sc = lane & 7;

    f32x4 acc[2][4];
    #pragma unroll
    for (int i = 0; i < 2; ++i)
        #pragma unroll
        for (int j = 0; j < 4; ++j) acc[i][j] = (f32x4){0.f, 0.f, 0.f, 0.f};

    for (int kt = 0; kt < Kdim; kt += 64) {
        #pragma unroll
        for (int p = 0; p < 2; ++p) {
            const int rbase = wv * 16 + p * 8;
            gload_lds16(A  + (size_t)(m0 + rbase + sr) * Kdim + kt + sc * 8,
                        As + rbase * 64);
            gload_lds16(Bt + (size_t)(n0 + rbase + sr) * Kdim + kt + sc * 8,
                        Bs + rbase * 64);
        }
        __syncthreads();
        #pragma unroll
        for (int s = 0; s < 2; ++s) {
            bf16x8 af[2], bfb[4];
            #pragma unroll
            for (int i = 0; i < 2; ++i)
                af[i] = *(const bf16x8*)(As + (wm * 32 + i * 16 + L) * 64 + s * 32 + qd * 8);
            #pragma unroll
            for (int j = 0; j < 4; ++j)
                bfb[j] = *(const bf16x8*)(Bs + (wn * 64 + j * 16 + L) * 64 + s * 32 + qd * 8);
            #pragma unroll
            for (int i = 0; i < 2; ++i)
                #pragma unroll
                for (int j = 0; j < 4; ++j)
                    acc[i][j] = __builtin_amdgcn_mfma_f32_16x16x32_bf16(af[i], bfb[j], acc[i][j], 0, 0, 0);
        }
        __syncthreads();
    }

    #pragma unroll
    for (int j = 0; j < 4; ++j) {
        const int col = n0 + wn * 64 + j * 16 + L;
        const float bv = bias[col];
        #pragma unroll
        for (int i = 0; i < 2; ++i) {
            const int rowb = m0 + wm * 32 + i * 16 + qd * 4;
            if (EPI == 1 && col >= 1024) {
                ushort4 pk; unsigned short* pp = (unsigned short*)&pk;
                #pragma unroll
                for (int r = 0; r < 4; ++r) pp[r] = f2bf(acc[i][j][r] + bv);
                *(ushort4*)(vT + (size_t)(col - 1024) * 2048 + rowb) = pk;
            } else {
                #pragma unroll
                for (int r = 0; r < 4; ++r) {
                    float v = acc[i][j][r] + bv;
                    if (ACT == 2) v = 0.5f * v * (1.0f + erff(v * 0.70710678118654752f));
                    Cb[(size_t)(rowb + r) * N + col] = f2bf(v);
                }
            }
        }
    }
}

// ---------------------------------------------------------------------------
// 64x64 MFMA GEMM (R2/R3-proven), 256 thr = 4 waves, wave = 16 rows x 64 cols.
// ---------------------------------------------------------------------------
template<int ACT>
__global__ __launch_bounds__(256) void mfma_gemm64(
    const unsigned short* __restrict__ A, const unsigned short* __restrict__ Bt,
    const float* __restrict__ bias, unsigned short* __restrict__ Cb,
    int M, int N, int Kdim)
{
    __shared__ unsigned short As[64 * 64];
    __shared__ unsigned short Bs[64 * 64];

    const int t = threadIdx.x, lane = t & 63, wv = t >> 6;
    const int n0 = blockIdx.x * 64, m0 = blockIdx.y * 64;
    const int r8 = lane >> 3, c8 = lane & 7;
    const int L = lane & 15, qd = lane >> 4;

    f32x4 acc[4];
    #pragma unroll
    for (int j = 0; j < 4; ++j) acc[j] = (f32x4){0.f, 0.f, 0.f, 0.f};

    for (int kt = 0; kt < Kdim; kt += 64) {
        #pragma unroll
        for (int i = 0; i < 2; ++i) {
            const int rbase = wv * 16 + i * 8;
            gload_lds16(A  + (size_t)(m0 + rbase + r8) * Kdim + kt + c8 * 8, As + rbase * 64);
            gload_lds16(Bt + (size_t)(n0 + rbase + r8) * Kdim + kt + c8 * 8, Bs + rbase * 64);
        }
        __syncthreads();
        #pragma unroll
        for (int s = 0; s < 2; ++s) {
            const bf16x8 a = *(const bf16x8*)(As + (wv * 16 + L) * 64 + s * 32 + qd * 8);
            #pragma unroll
            for (int j = 0; j < 4; ++j) {
                const bf16x8 b = *(const bf16x8*)(Bs + (j * 16 + L) * 64 + s * 32 + qd * 8);
                acc[j] = __builtin_amdgcn_mfma_f32_16x16x32_bf16(a, b, acc[j], 0, 0, 0);
            }
        }
        __syncthreads();
    }

    #pragma unroll
    for (int j = 0; j < 4; ++j) {
        const int col = n0 + j * 16 + L;
        const float bv = bias[col];
        #pragma unroll
        for (int r = 0; r < 4; ++r) {
            const int row = m0 + wv * 16 + qd * 4 + r;
            float v = acc[j][r] + bv;
            if (ACT == 1) v = v / (1.0f + __expf(-v));
            Cb[(size_t)row * N + col] = f2bf(v);
        }
    }
}

// ---------------------------------------------------------------------------
// Fused GEMM + bias + residual + LayerNorm.  C[16 rows][512 cols] per block,
// 128 blocks, 256 thr = 4 waves; wave w owns cols [w*128, w*128+128).
// out = LN(A@Bt^T + bias + res)*g + be.  KD = inner dim (512 or 2048).
// ---------------------------------------------------------------------------
template<int KD, int OUT16>
__global__ __launch_bounds__(256) void gemm_ln(
    const unsigned short* __restrict__ A, const unsigned short* __restrict__ Bt,
    const float* __restrict__ bias, const float* __restrict__ res,
    const float* __restrict__ g, const float* __restrict__ be,
    float* __restrict__ out, unsigned short* __restrict__ outb)
{
    __shared__ unsigned short As[16 * 64];     // 2 KB
    __shared__ unsigned short Bs[512 * 64];    // 64 KB
    __shared__ float red1[4][16];
    __shared__ float red2[4][16];

    const int t = threadIdx.x, lane = t & 63, wv = t >> 6;
    const int L = lane & 15, qd = lane >> 4;
    const int m0 = blockIdx.x * 16;

    f32x4 acc[8];
    #pragma unroll
    for (int j = 0; j < 8; ++j) acc[j] = (f32x4){0.f, 0.f, 0.f, 0.f};

    for (int kt = 0; kt < KD; kt += 64) {
        if (t < 128)
            gload_lds16(A + (size_t)(m0 + (t >> 3)) * KD + kt + (t & 7) * 8,
                        As + (t >> 3) * 64);
        #pragma unroll
        for (int i = 0; i < 16; ++i)
            gload_lds16(Bt + (size_t)(i * 32 + (t >> 3)) * KD + kt + (t & 7) * 8,
                        Bs + (i * 32 + (t >> 3)) * 64);
        __syncthreads();
        #pragma unroll
        for (int s = 0; s < 2; ++s) {
            const bf16x8 a = *(const bf16x8*)(As + L * 64 + s * 32 + qd * 8);
            #pragma unroll
            for (int j = 0; j < 8; ++j) {
                const bf16x8 b = *(const bf16x8*)(Bs + (wv * 128 + j * 16 + L) * 64 + s * 32 + qd * 8);
                acc[j] = __builtin_amdgcn_mfma_f32_16x16x32_bf16(a, b, acc[j], 0, 0, 0);
            }
        }
        __syncthreads();
    }

    // val[j][r] = C[row=qd*4+r][col=wv*128+j*16+L] + bias + residual
    float val[8][4];
    #pragma unroll
    for (int j = 0; j < 8; ++j) {
        const int col = wv * 128 + j * 16 + L;
        const float bv = bias[col];
        #pragma unroll
        for (int r = 0; r < 4; ++r) {
            const int row = m0 + qd * 4 + r;
            val[j][r] = acc[j][r] + bv + res[(size_t)row * DD + col];
        }
    }

    // row sums -> mean
    float s[4] = {0.f, 0.f, 0.f, 0.f};
    #pragma unroll
    for (int j = 0; j < 8; ++j)
        #pragma unroll
        for (int r = 0; r < 4; ++r) s[r] += val[j][r];
    #pragma unroll
    for (int off = 8; off > 0; off >>= 1)
        #pragma unroll
        for (int r = 0; r < 4; ++r) s[r] += __shfl_xor(s[r], off);
    if (L == 0) {
        #pragma unroll
        for (int r = 0; r < 4; ++r) red1[wv][qd * 4 + r] = s[r];
    }
    __syncthreads();
    float mean[4];
    #pragma unroll
    for (int r = 0; r < 4; ++r) {
        const int rr = qd * 4 + r;
        mean[r] = (red1[0][rr] + red1[1][rr] + red1[2][rr] + red1[3][rr]) * (1.0f / 512.0f);
    }

    // centered squares -> var
    float v2[4] = {0.f, 0.f, 0.f, 0.f};
    #pragma unroll
    for (int j = 0; j < 8; ++j)
        #pragma unroll
        for (int r = 0; r < 4; ++r) {
            const float d = val[j][r] - mean[r];
            val[j][r] = d;
            v2[r] += d * d;
        }
    #pragma unroll
    for (int off = 8; off > 0; off >>= 1)
        #pragma unroll
        for (int r = 0; r < 4; ++r) v2[r] += __shfl_xor(v2[r], off);
    if (L == 0) {
        #pragma unroll
        for (int r = 0; r < 4; ++r) red2[wv][qd * 4 + r] = v2[r];
    }
    __syncthreads();
    float inv[4];
    #pragma unroll
    for (int r = 0; r < 4; ++r) {
        const int rr = qd * 4 + r;
        const float var = (red2[0][rr] + red2[1][rr] + red2[2][rr] + red2[3][rr]) * (1.0f / 512.0f);
        inv[r] = rsqrtf(var + 1e-6f);
    }

    #pragma unroll
    for (int j = 0; j < 8; ++j) {
        const int col = wv * 128 + j * 16 + L;
        const float gc = g[col], bc = be[col];
        #pragma unroll
        for (int r = 0; r < 4; ++r) {
            const int row = m0 + qd * 4 + r;
            const float o = val[j][r] * inv[r] * gc + bc;
            out[(size_t)row * DD + col] = o;
            if (OUT16) outb[(size_t)row * DD + col] = f2bf(o);
        }
    }
}

// ---------------------------------------------------------------------------
// MFMA attention (R3/R4-proven): one block per (b, h, 64-query tile).
// ---------------------------------------------------------------------------
__global__ __launch_bounds__(256) void attn_kernel(
    const unsigned short* __restrict__ qkvb, const unsigned short* __restrict__ vT,
    const unsigned short* __restrict__ biasMs, unsigned short* __restrict__ msgT)
{
    const int qt = blockIdx.x, h = blockIdx.y, b = blockIdx.z;
    const int q0 = qt * 64;
    const int t = threadIdx.x, lane = t & 63, wv = t >> 6;
    const int L = lane & 15, qd = lane >> 4;

    __shared__ unsigned short Qs[64 * 32];
    __shared__ unsigned short Ks[256 * 32];
    __shared__ unsigned short Vs[32 * 264];
    __shared__ unsigned short Ps[64 * 264];
    __shared__ unsigned short Ot[32 * 72];

    {
        const int r = lane >> 2, c = lane & 3;
        gload_lds16(qkvb + (size_t)(b * NN + q0 + wv * 16 + r) * 1536 + h * DKK + c * 8,
                    Qs + wv * 16 * 32);
        #pragma unroll
        for (int p = 0; p < 4; ++p)
            gload_lds16(qkvb + (size_t)(b * NN + p * 64 + wv * 16 + r) * 1536 + 512 + h * DKK + c * 8,
                        Ks + (p * 64 + wv * 16) * 32);
    }
    {
        const int vr = t >> 3, seg = t & 7;
        const unsigned short* gv = vT + (size_t)(h * DKK + vr) * 2048 + b * NN + seg * 32;
        #pragma unroll
        for (int i = 0; i < 4; ++i) {
            bf16x8 vv = *(const bf16x8*)(gv + i * 8);
            *(bf16x8*)(Vs + vr * 264 + seg * 32 + i * 8) = vv;
        }
    }
    __syncthreads();

    f32x4 S[16];
    #pragma unroll
    for (int j = 0; j < 16; ++j) S[j] = (f32x4){0.f, 0.f, 0.f, 0.f};
    {
        const bf16x8 aq = *(const bf16x8*)(Qs + (wv * 16 + L) * 32 + qd * 8);
        #pragma unroll
        for (int j = 0; j < 16; ++j) {
            const bf16x8 bk = *(const bf16x8*)(Ks + (j * 16 + L) * 32 + qd * 8);
            S[j] = __builtin_amdgcn_mfma_f32_16x16x32_bf16(aq, bk, S[j], 0, 0, 0);
        }
    }
    const float scale = 0.17677669529663687f;
    const int rgb = (q0 + wv * 16) >> 2;

    for (int ks = 0; ks < KK; ++ks) {
        const unsigned short* bp = biasMs + ((size_t)((b * KK + ks) * 64 + rgb + qd)) * 1024;

        ushort4 b4[16];
        float mx[4] = {-3e38f, -3e38f, -3e38f, -3e38f};
        #pragma unroll
        for (int j = 0; j < 16; ++j) {
            b4[j] = *(const ushort4*)(bp + (j * 16 + L) * 4);
            const unsigned short* pb = (const unsigned short*)&b4[j];
            #pragma unroll
            for (int r = 0; r < 4; ++r)
                mx[r] = fmaxf(mx[r], S[j][r] * scale + bf2f(pb[r]));
        }
        #pragma unroll
        for (int off = 8; off > 0; off >>= 1)
            #pragma unroll
            for (int r = 0; r < 4; ++r) mx[r] = fmaxf(mx[r], __shfl_xor(mx[r], off));

        float sm[4] = {0.f, 0.f, 0.f, 0.f};
        #pragma unroll
        for (int j = 0; j < 16; ++j) {
            const unsigned short* pb = (const unsigned short*)&b4[j];
            #pragma unroll
            for (int r = 0; r < 4; ++r) {
                const float e = __expf(S[j][r] * scale + bf2f(pb[r]) - mx[r]);
                sm[r] += e;
                Ps[(wv * 16 + qd * 4 + r) * 264 + j * 16 + L] = f2bf(e);
            }
        }
        #pragma unroll
        for (int off = 8; off > 0; off >>= 1)
            #pragma unroll
            for (int r = 0; r < 4; ++r) sm[r] += __shfl_xor(sm[r], off);
        float inv[4];
        #pragma unroll
        for (int r = 0; r < 4; ++r) inv[r] = 1.0f / sm[r];

        f32x4 O[2];
        O[0] = (f32x4){0.f, 0.f, 0.f, 0.f};
        O[1] = (f32x4){0.f, 0.f, 0.f, 0.f};
        #pragma unroll
        for (int kc = 0; kc < 8; ++kc) {
            const bf16x8 ap = *(const bf16x8*)(Ps + (wv * 16 + L) * 264 + kc * 32 + qd * 8);
            #pragma unroll
            for (int jt = 0; jt < 2; ++jt) {
                const bf16x8 bv = *(const bf16x8*)(Vs + (jt * 16 + L) * 264 + kc * 32 + qd * 8);
                O[jt] = __builtin_amdgcn_mfma_f32_16x16x32_bf16(ap, bv, O[jt], 0, 0, 0);
            }
        }
        #pragma unroll
        for (int jt = 0; jt < 2; ++jt)
            #pragma unroll
            for (int r = 0; r < 4; ++r)
                Ot[(jt * 16 + L) * 72 + wv * 16 + qd * 4 + r] = f2bf(O[jt][r] * inv[r]);
        __syncthreads();

        {
            const int dd = t >> 3, cc = t & 7;
            bf16x8 ov = *(const bf16x8*)(Ot + dd * 72 + cc * 8);
            *(bf16x8*)(msgT + (size_t)b * 524288 +
                       ((size_t)((ks * HH + h) * DKK + dd)) * NN + q0 + cc * 8) = ov;
        }
        __syncthreads();
    }
}

// ---------------------------------------------------------------------------
extern "C" void kernel_launch(void* const* d_in, const int* in_sizes, int n_in,
                              void* d_out, int out_size, void* d_ws, size_t ws_size,
                              hipStream_t stream)
{
    const float* x         = (const float*)d_in[0];
    const float* dist      = (const float*)d_in[1];
    const float* dist_bar  = (const float*)d_in[2];
    const float* attn_bias = (const float*)d_in[3];
    const int*   mask      = (const int*)d_in[4];
    const float* Wq  = (const float*)d_in[6];  const float* bq  = (const float*)d_in[7];
    const float* Wk  = (const float*)d_in[8];  const float* bk  = (const float*)d_in[9];
    const float* Wv  = (const float*)d_in[10]; const float* bv  = (const float*)d_in[11];
    const float* W1  = (const float*)d_in[12]; const float* b1  = (const float*)d_in[13];
    const float* W2  = (const float*)d_in[14]; const float* b2  = (const float*)d_in[15];
    const float* g1  = (const float*)d_in[16]; const float* be1 = (const float*)d_in[17];
    const float* Wf1 = (const float*)d_in[18]; const float* bf1 = (const float*)d_in[19];
    const float* Wf2 = (const float*)d_in[20]; const float* bf2 = (const float*)d_in[21];
    const float* g2  = (const float*)d_in[22]; const float* be2 = (const float*)d_in[23];

    float* ws = (float*)d_ws;
    unsigned short* qkvb   = (unsigned short*)(ws + 0);          // bf16 [2048][1536]
    unsigned short* vT     = (unsigned short*)(ws + 1572864);    // bf16 [512][2048]
    unsigned short* xb     = (unsigned short*)(ws + 2097152);    // bf16 [2048][512]
    unsigned short* msgT   = (unsigned short*)(ws + 2621440);    // bf16 [8][2048][256] -> g3
    unsigned short* g3     = msgT;                               // bf16 [2048][2048]
    unsigned short* biasMs = (unsigned short*)(ws + 4718592);    // bf16 [2048][1024]
    float*          bqkv   = ws + 5767168;                       // f32 [1536]
    unsigned short* h1     = (unsigned short*)(ws + 5771264);    // bf16 [2048][512]
    float*          yb     = ws + 6295552;                       // f32 [2048][512]
    unsigned short* yb16   = (unsigned short*)(ws + 7344128);    // bf16 [2048][512]
    unsigned short* Wqkvt  = (unsigned short*)(ws + 7868416);    // bf16 [1536][512]
    unsigned short* W1t    = (unsigned short*)(ws + 8261632);    // bf16 [512][2048]
    unsigned short* W2t    = (unsigned short*)(ws + 8785920);    // bf16 [512][512]
    unsigned short* Wf1t   = (unsigned short*)(ws + 8916992);    // bf16 [2048][512]
    unsigned short* Wf2t   = (unsigned short*)(ws + 9441280);    // bf16 [512][2048]
    float*          outp   = (float*)d_out;

    const int M = BB * NN;  // 2048

    // 1) prep: weights, x, bqkv, biasMs
    prep_kernel<<<dim3(2048, 1, 10), dim3(256), 0, stream>>>(
        x, Wq, Wk, Wv, W1, W2, Wf1, Wf2, bq, bk, bv,
        attn_bias, mask, dist, dist_bar,
        xb, Wqkvt, W1t, W2t, Wf1t, Wf2t, bqkv, biasMs);

    // 2) fused QKV; v written transposed into vT
    mfma_gemm512<0, 1><<<dim3(12, 16), dim3(512), 0, stream>>>(
        xb, Wqkvt, bqkv, qkvb, vT, M, 1536, DD);

    // 3) 4-scale MFMA attention -> bf16 msgT (scrambled W1-input layout)
    attn_kernel<<<dim3(4, HH, BB), dim3(256), 0, stream>>>(qkvb, vT, biasMs, msgT);

    // 4) h1 = silu(msgT @ W1 + b1)
    mfma_gemm64<1><<<dim3(8, 32), dim3(256), 0, stream>>>(msgT, W1t, b1, h1, M, DD, 2048);

    // 5) y = LN(h1 @ W2 + b2 + x)   (fused GEMM+residual+LN)
    gemm_ln<512, 1><<<dim3(128), dim3(256), 0, stream>>>(
        h1, W2t, b2, x, g1, be1, yb, yb16);

    // 6) g3 = gelu(y @ Wf1 + bf1)
    mfma_gemm512<2, 0><<<dim3(16, 16), dim3(512), 0, stream>>>(
        yb16, Wf1t, bf1, g3, nullptr, M, FFN_, DD);

    // 7) out = LN(g3 @ Wf2 + bf2 + y)   (fused GEMM+residual+LN)
    gemm_ln<2048, 0><<<dim3(128), dim3(256), 0, stream>>>(
        g3, Wf2t, bf2, yb, g2, be2, outp, nullptr);
}

// Round 8
// 262.985 us; speedup vs baseline: 2.0124x; 1.0779x over previous
//
#include <hip/hip_runtime.h>
#include <math.h>

#define BB 8
#define NN 256
#define DD 512
#define HH 16
#define KK 4
#define DKK 32
#define FFN_ 2048
#define NEGV -1e12f

typedef __attribute__((ext_vector_type(8))) short bf16x8;
typedef __attribute__((ext_vector_type(4))) float f32x4;

__device__ __forceinline__ unsigned short f2bf(float f) {
    union { float f; unsigned int u; } v; v.f = f;
    unsigned int r = (v.u + 0x7FFFu + ((v.u >> 16) & 1u)) >> 16;
    return (unsigned short)r;
}
__device__ __forceinline__ float bf2f(unsigned short u) {
    union { unsigned int i; float f; } v; v.i = ((unsigned int)u) << 16;
    return v.f;
}
__device__ __forceinline__ void gload_lds16(const unsigned short* g, unsigned short* l) {
    __builtin_amdgcn_global_load_lds(
        (const __attribute__((address_space(1))) void*)g,
        (__attribute__((address_space(3))) void*)l, 16, 0, 0);
}

// ---------------------------------------------------------------------------
// Merged prep (R4-proven): z=0..6 weight transposes fp32->bf16 Wt[N][K];
// z=7 x->bf16; z=8 bias concat; z=9 mask+dist+bias combine (biasMs).
// ---------------------------------------------------------------------------
__global__ __launch_bounds__(256) void prep_kernel(
    const float* __restrict__ x,
    const float* __restrict__ Wq, const float* __restrict__ Wk,
    const float* __restrict__ Wv, const float* __restrict__ W1,
    const float* __restrict__ W2, const float* __restrict__ Wf1,
    const float* __restrict__ Wf2,
    const float* __restrict__ bq, const float* __restrict__ bk,
    const float* __restrict__ bv,
    const float* __restrict__ attn_bias, const int* __restrict__ mask,
    const float* __restrict__ dist, const float* __restrict__ dist_bar,
    unsigned short* __restrict__ xb, unsigned short* __restrict__ Wqkvt,
    unsigned short* __restrict__ W1t, unsigned short* __restrict__ W2t,
    unsigned short* __restrict__ Wf1t, unsigned short* __restrict__ Wf2t,
    float* __restrict__ bqkv, unsigned short* __restrict__ biasMs)
{
    const int z = blockIdx.z;
    const int t = threadIdx.x;

    if (z == 7) {
        if (blockIdx.x >= 1024) return;
        const int i0 = blockIdx.x * 1024 + t * 4;
        float4 xv = *(const float4*)(x + i0);
        ushort4 o;
        o.x = f2bf(xv.x); o.y = f2bf(xv.y); o.z = f2bf(xv.z); o.w = f2bf(xv.w);
        *(ushort4*)(xb + i0) = o;
        return;
    }
    if (z == 8) {
        if (blockIdx.x >= 6) return;
        const int i = blockIdx.x * 256 + t;
        float v = (i < 512) ? bq[i] : (i < 1024) ? bk[i - 512] : bv[i - 1024];
        bqkv[i] = v;
        return;
    }
    if (z == 9) {
        const int bx = blockIdx.x;
        const int rg = bx & 63, ks = (bx >> 6) & 3, b = bx >> 8;
        const int m = t;
        const float bar = dist_bar[ks];
        ushort4 o; unsigned short* po = (unsigned short*)&o;
        #pragma unroll
        for (int i = 0; i < 4; ++i) {
            const int n = rg * 4 + i;
            const int mk = mask[((size_t)(b * NN) + n) * NN + m];
            bool allowed = (n == 0) || (m == 0);
            if (!allowed)
                allowed = dist[((size_t)(b * 255) + (n - 1)) * 255 + (m - 1)] < bar;
            const float bias = attn_bias[(((size_t)(b * KK) + ks) * NN + n) * NN + m];
            po[i] = f2bf((mk != 0 && allowed) ? bias : NEGV);
        }
        *(ushort4*)(biasMs + (size_t)bx * 1024 + m * 4) = o;
        return;
    }

    const float* src; unsigned short* dst; int Kd, Nd;
    switch (z) {
        case 0: src = Wq;  dst = Wqkvt;              Kd = 512;  Nd = 512;  break;
        case 1: src = Wk;  dst = Wqkvt + 512 * 512;  Kd = 512;  Nd = 512;  break;
        case 2: src = Wv;  dst = Wqkvt + 1024 * 512; Kd = 512;  Nd = 512;  break;
        case 3: src = W1;  dst = W1t;  Kd = 2048; Nd = 512;  break;
        case 4: src = W2;  dst = W2t;  Kd = 512;  Nd = 512;  break;
        case 5: src = Wf1; dst = Wf1t; Kd = 512;  Nd = 2048; break;
        default: src = Wf2; dst = Wf2t; Kd = 2048; Nd = 512; break;
    }
    const int ktiles = Kd / 32, ntiles = Nd / 32;
    const int ti = blockIdx.x;
    if (ti >= ktiles * ntiles) return;
    const int k0 = (ti % ktiles) * 32, n0 = (ti / ktiles) * 32;

    __shared__ float tile[32][33];
    const int xx = t & 31, yy = t >> 5;
    #pragma unroll
    for (int r = 0; r < 4; ++r)
        tile[yy * 4 + r][xx] = src[(size_t)(k0 + yy * 4 + r) * Nd + n0 + xx];
    __syncthreads();
    #pragma unroll
    for (int r = 0; r < 4; ++r)
        dst[(size_t)(n0 + yy * 4 + r) * Kd + k0 + xx] = f2bf(tile[xx][yy * 4 + r]);
}

// ---------------------------------------------------------------------------
// 512-thread 128x128 MFMA GEMM (R4-proven), 8 waves (4m x 2n), BK=64.
// EPI 0: bf16 out + ACT.  EPI 1: QKV split (col<1024 -> Cb pitch 1536, else
// vT transposed).
// ---------------------------------------------------------------------------
template<int ACT, int EPI>
__global__ __launch_bounds__(512) void mfma_gemm512(
    const unsigned short* __restrict__ A, const unsigned short* __restrict__ Bt,
    const float* __restrict__ bias, unsigned short* __restrict__ Cb,
    unsigned short* __restrict__ vT, int M, int N, int Kdim)
{
    __shared__ unsigned short As[128 * 64];
    __shared__ unsigned short Bs[128 * 64];

    const int t = threadIdx.x, lane = t & 63, wv = t >> 6;
    const int n0 = blockIdx.x * 128, m0 = blockIdx.y * 128;
    const int wm = wv >> 1, wn = wv & 1;
    const int L = lane & 15, qd = lane >> 4;
    const int sr = lane >> 3, sc = lane & 7;

    f32x4 acc[2][4];
    #pragma unroll
    for (int i = 0; i < 2; ++i)
        #pragma unroll
        for (int j = 0; j < 4; ++j) acc[i][j] = (f32x4){0.f, 0.f, 0.f, 0.f};

    for (int kt = 0; kt < Kdim; kt += 64) {
        #pragma unroll
        for (int p = 0; p < 2; ++p) {
            const int rbase = wv * 16 + p * 8;
            gload_lds16(A  + (size_t)(m0 + rbase + sr) * Kdim + kt + sc * 8,
                        As + rbase * 64);
            gload_lds16(Bt + (size_t)(n0 + rbase + sr) * Kdim + kt + sc * 8,
                        Bs + rbase * 64);
        }
        __syncthreads();
        #pragma unroll
        for (int s = 0; s < 2; ++s) {
            bf16x8 af[2], bfb[4];
            #pragma unroll
            for (int i = 0; i < 2; ++i)
                af[i] = *(const bf16x8*)(As + (wm * 32 + i * 16 + L) * 64 + s * 32 + qd * 8);
            #pragma unroll
            for (int j = 0; j < 4; ++j)
                bfb[j] = *(const bf16x8*)(Bs + (wn * 64 + j * 16 + L) * 64 + s * 32 + qd * 8);
            #pragma unroll
            for (int i = 0; i < 2; ++i)
                #pragma unroll
                for (int j = 0; j < 4; ++j)
                    acc[i][j] = __builtin_amdgcn_mfma_f32_16x16x32_bf16(af[i], bfb[j], acc[i][j], 0, 0, 0);
        }
        __syncthreads();
    }

    #pragma unroll
    for (int j = 0; j < 4; ++j) {
        const int col = n0 + wn * 64 + j * 16 + L;
        const float bv = bias[col];
        #pragma unroll
        for (int i = 0; i < 2; ++i) {
            const int rowb = m0 + wm * 32 + i * 16 + qd * 4;
            if (EPI == 1 && col >= 1024) {
                ushort4 pk; unsigned short* pp = (unsigned short*)&pk;
                #pragma unroll
                for (int r = 0; r < 4; ++r) pp[r] = f2bf(acc[i][j][r] + bv);
                *(ushort4*)(vT + (size_t)(col - 1024) * 2048 + rowb) = pk;
            } else {
                #pragma unroll
                for (int r = 0; r < 4; ++r) {
                    float v = acc[i][j][r] + bv;
                    if (ACT == 2) v = 0.5f * v * (1.0f + erff(v * 0.70710678118654752f));
                    Cb[(size_t)(rowb + r) * N + col] = f2bf(v);
                }
            }
        }
    }
}

// ---------------------------------------------------------------------------
// 64x64 MFMA GEMM (R2/R3-proven), 256 thr = 4 waves, wave = 16 rows x 64 cols.
// ACT 1 = silu. OUTF32: fp32 out (Cf) else bf16 (Cb).
// ---------------------------------------------------------------------------
template<int ACT, int OUTF32>
__global__ __launch_bounds__(256) void mfma_gemm64(
    const unsigned short* __restrict__ A, const unsigned short* __restrict__ Bt,
    const float* __restrict__ bias, unsigned short* __restrict__ Cb,
    float* __restrict__ Cf, int M, int N, int Kdim)
{
    __shared__ unsigned short As[64 * 64];
    __shared__ unsigned short Bs[64 * 64];

    const int t = threadIdx.x, lane = t & 63, wv = t >> 6;
    const int n0 = blockIdx.x * 64, m0 = blockIdx.y * 64;
    const int r8 = lane >> 3, c8 = lane & 7;
    const int L = lane & 15, qd = lane >> 4;

    f32x4 acc[4];
    #pragma unroll
    for (int j = 0; j < 4; ++j) acc[j] = (f32x4){0.f, 0.f, 0.f, 0.f};

    for (int kt = 0; kt < Kdim; kt += 64) {
        #pragma unroll
        for (int i = 0; i < 2; ++i) {
            const int rbase = wv * 16 + i * 8;
            gload_lds16(A  + (size_t)(m0 + rbase + r8) * Kdim + kt + c8 * 8, As + rbase * 64);
            gload_lds16(Bt + (size_t)(n0 + rbase + r8) * Kdim + kt + c8 * 8, Bs + rbase * 64);
        }
        __syncthreads();
        #pragma unroll
        for (int s = 0; s < 2; ++s) {
            const bf16x8 a = *(const bf16x8*)(As + (wv * 16 + L) * 64 + s * 32 + qd * 8);
            #pragma unroll
            for (int j = 0; j < 4; ++j) {
                const bf16x8 b = *(const bf16x8*)(Bs + (j * 16 + L) * 64 + s * 32 + qd * 8);
                acc[j] = __builtin_amdgcn_mfma_f32_16x16x32_bf16(a, b, acc[j], 0, 0, 0);
            }
        }
        __syncthreads();
    }

    #pragma unroll
    for (int j = 0; j < 4; ++j) {
        const int col = n0 + j * 16 + L;
        const float bv = bias[col];
        #pragma unroll
        for (int r = 0; r < 4; ++r) {
            const int row = m0 + wv * 16 + qd * 4 + r;
            float v = acc[j][r] + bv;
            if (ACT == 1) v = v / (1.0f + __expf(-v));
            if (OUTF32) Cf[(size_t)row * N + col] = v;
            else        Cb[(size_t)row * N + col] = f2bf(v);
        }
    }
}

// ---------------------------------------------------------------------------
// Per-wave LayerNorm (barrier-free): 4 waves/block, wave = 1 row of 512.
// out = LN(a + r)*g + be.  OUT16: also write bf16 copy.
// ---------------------------------------------------------------------------
template<int OUT16>
__global__ __launch_bounds__(256) void ln_kernel(
    const float* __restrict__ a, const float* __restrict__ r,
    const float* __restrict__ g, const float* __restrict__ be,
    float* __restrict__ out, unsigned short* __restrict__ outb)
{
    const int t = threadIdx.x, lane = t & 63, wv = t >> 6;
    const int row = blockIdx.x * 4 + wv;
    const size_t base = (size_t)row * DD + lane * 8;
    const int c0 = lane * 8;

    float z[8]; float s = 0.f;
    #pragma unroll
    for (int i = 0; i < 8; ++i) { z[i] = a[base + i] + r[base + i]; s += z[i]; }
    #pragma unroll
    for (int off = 32; off > 0; off >>= 1) s += __shfl_xor(s, off);
    const float mean = s * (1.0f / 512.0f);
    float v = 0.f;
    #pragma unroll
    for (int i = 0; i < 8; ++i) { z[i] -= mean; v += z[i] * z[i]; }
    #pragma unroll
    for (int off = 32; off > 0; off >>= 1) v += __shfl_xor(v, off);
    const float inv = rsqrtf(v * (1.0f / 512.0f) + 1e-6f);

    unsigned short o16[8];
    #pragma unroll
    for (int i = 0; i < 8; ++i) {
        const float o = z[i] * inv * g[c0 + i] + be[c0 + i];
        out[base + i] = o;
        if (OUT16) o16[i] = f2bf(o);
    }
    if (OUT16) *(bf16x8*)(outb + base) = *(bf16x8*)o16;
}

// ---------------------------------------------------------------------------
// MFMA attention (R3/R4-proven): one block per (b, h, 64-query tile).
// ---------------------------------------------------------------------------
__global__ __launch_bounds__(256) void attn_kernel(
    const unsigned short* __restrict__ qkvb, const unsigned short* __restrict__ vT,
    const unsigned short* __restrict__ biasMs, unsigned short* __restrict__ msgT)
{
    const int qt = blockIdx.x, h = blockIdx.y, b = blockIdx.z;
    const int q0 = qt * 64;
    const int t = threadIdx.x, lane = t & 63, wv = t >> 6;
    const int L = lane & 15, qd = lane >> 4;

    __shared__ unsigned short Qs[64 * 32];
    __shared__ unsigned short Ks[256 * 32];
    __shared__ unsigned short Vs[32 * 264];
    __shared__ unsigned short Ps[64 * 264];
    __shared__ unsigned short Ot[32 * 72];

    {
        const int r = lane >> 2, c = lane & 3;
        gload_lds16(qkvb + (size_t)(b * NN + q0 + wv * 16 + r) * 1536 + h * DKK + c * 8,
                    Qs + wv * 16 * 32);
        #pragma unroll
        for (int p = 0; p < 4; ++p)
            gload_lds16(qkvb + (size_t)(b * NN + p * 64 + wv * 16 + r) * 1536 + 512 + h * DKK + c * 8,
                        Ks + (p * 64 + wv * 16) * 32);
    }
    {
        const int vr = t >> 3, seg = t & 7;
        const unsigned short* gv = vT + (size_t)(h * DKK + vr) * 2048 + b * NN + seg * 32;
        #pragma unroll
        for (int i = 0; i < 4; ++i) {
            bf16x8 vv = *(const bf16x8*)(gv + i * 8);
            *(bf16x8*)(Vs + vr * 264 + seg * 32 + i * 8) = vv;
        }
    }
    __syncthreads();

    f32x4 S[16];
    #pragma unroll
    for (int j = 0; j < 16; ++j) S[j] = (f32x4){0.f, 0.f, 0.f, 0.f};
    {
        const bf16x8 aq = *(const bf16x8*)(Qs + (wv * 16 + L) * 32 + qd * 8);
        #pragma unroll
        for (int j = 0; j < 16; ++j) {
            const bf16x8 bk = *(const bf16x8*)(Ks + (j * 16 + L) * 32 + qd * 8);
            S[j] = __builtin_amdgcn_mfma_f32_16x16x32_bf16(aq, bk, S[j], 0, 0, 0);
        }
    }
    const float scale = 0.17677669529663687f;
    const int rgb = (q0 + wv * 16) >> 2;

    for (int ks = 0; ks < KK; ++ks) {
        const unsigned short* bp = biasMs + ((size_t)((b * KK + ks) * 64 + rgb + qd)) * 1024;

        ushort4 b4[16];
        float mx[4] = {-3e38f, -3e38f, -3e38f, -3e38f};
        #pragma unroll
        for (int j = 0; j < 16; ++j) {
            b4[j] = *(const ushort4*)(bp + (j * 16 + L) * 4);
            const unsigned short* pb = (const unsigned short*)&b4[j];
            #pragma unroll
            for (int r = 0; r < 4; ++r)
                mx[r] = fmaxf(mx[r], S[j][r] * scale + bf2f(pb[r]));
        }
        #pragma unroll
        for (int off = 8; off > 0; off >>= 1)
            #pragma unroll
            for (int r = 0; r < 4; ++r) mx[r] = fmaxf(mx[r], __shfl_xor(mx[r], off));

        float sm[4] = {0.f, 0.f, 0.f, 0.f};
        #pragma unroll
        for (int j = 0; j < 16; ++j) {
            const unsigned short* pb = (const unsigned short*)&b4[j];
            #pragma unroll
            for (int r = 0; r < 4; ++r) {
                const float e = __expf(S[j][r] * scale + bf2f(pb[r]) - mx[r]);
                sm[r] += e;
                Ps[(wv * 16 + qd * 4 + r) * 264 + j * 16 + L] = f2bf(e);
            }
        }
        #pragma unroll
        for (int off = 8; off > 0; off >>= 1)
            #pragma unroll
            for (int r = 0; r < 4; ++r) sm[r] += __shfl_xor(sm[r], off);
        float inv[4];
        #pragma unroll
        for (int r = 0; r < 4; ++r) inv[r] = 1.0f / sm[r];

        f32x4 O[2];
        O[0] = (f32x4){0.f, 0.f, 0.f, 0.f};
        O[1] = (f32x4){0.f, 0.f, 0.f, 0.f};
        #pragma unroll
        for (int kc = 0; kc < 8; ++kc) {
            const bf16x8 ap = *(const bf16x8*)(Ps + (wv * 16 + L) * 264 + kc * 32 + qd * 8);
            #pragma unroll
            for (int jt = 0; jt < 2; ++jt) {
                const bf16x8 bv = *(const bf16x8*)(Vs + (jt * 16 + L) * 264 + kc * 32 + qd * 8);
                O[jt] = __builtin_amdgcn_mfma_f32_16x16x32_bf16(ap, bv, O[jt], 0, 0, 0);
            }
        }
        #pragma unroll
        for (int jt = 0; jt < 2; ++jt)
            #pragma unroll
            for (int r = 0; r < 4; ++r)
                Ot[(jt * 16 + L) * 72 + wv * 16 + qd * 4 + r] = f2bf(O[jt][r] * inv[r]);
        __syncthreads();

        {
            const int dd = t >> 3, cc = t & 7;
            bf16x8 ov = *(const bf16x8*)(Ot + dd * 72 + cc * 8);
            *(bf16x8*)(msgT + (size_t)b * 524288 +
                       ((size_t)((ks * HH + h) * DKK + dd)) * NN + q0 + cc * 8) = ov;
        }
        __syncthreads();
    }
}

// ---------------------------------------------------------------------------
extern "C" void kernel_launch(void* const* d_in, const int* in_sizes, int n_in,
                              void* d_out, int out_size, void* d_ws, size_t ws_size,
                              hipStream_t stream)
{
    const float* x         = (const float*)d_in[0];
    const float* dist      = (const float*)d_in[1];
    const float* dist_bar  = (const float*)d_in[2];
    const float* attn_bias = (const float*)d_in[3];
    const int*   mask      = (const int*)d_in[4];
    const float* Wq  = (const float*)d_in[6];  const float* bq  = (const float*)d_in[7];
    const float* Wk  = (const float*)d_in[8];  const float* bk  = (const float*)d_in[9];
    const float* Wv  = (const float*)d_in[10]; const float* bv  = (const float*)d_in[11];
    const float* W1  = (const float*)d_in[12]; const float* b1  = (const float*)d_in[13];
    const float* W2  = (const float*)d_in[14]; const float* b2  = (const float*)d_in[15];
    const float* g1  = (const float*)d_in[16]; const float* be1 = (const float*)d_in[17];
    const float* Wf1 = (const float*)d_in[18]; const float* bf1 = (const float*)d_in[19];
    const float* Wf2 = (const float*)d_in[20]; const float* bf2 = (const float*)d_in[21];
    const float* g2  = (const float*)d_in[22]; const float* be2 = (const float*)d_in[23];

    float* ws = (float*)d_ws;
    unsigned short* qkvb   = (unsigned short*)(ws + 0);          // bf16 [2048][1536]
    unsigned short* vT     = (unsigned short*)(ws + 1572864);    // bf16 [512][2048]
    unsigned short* xb     = (unsigned short*)(ws + 2097152);    // bf16 [2048][512]
    unsigned short* msgT   = (unsigned short*)(ws + 2621440);    // bf16 [8][2048][256] -> g3
    unsigned short* g3     = msgT;                               // bf16 [2048][2048]
    unsigned short* biasMs = (unsigned short*)(ws + 4718592);    // bf16 [2048][1024]
    float*          bqkv   = ws + 5767168;                       // f32 [1536]
    unsigned short* h1     = (unsigned short*)(ws + 5771264);    // bf16 [2048][512]
    float*          yb     = ws + 6295552;                       // f32 [2048][512]
    unsigned short* yb16   = (unsigned short*)(ws + 7344128);    // bf16 [2048][512]
    unsigned short* Wqkvt  = (unsigned short*)(ws + 7868416);    // bf16 [1536][512]
    unsigned short* W1t    = (unsigned short*)(ws + 8261632);    // bf16 [512][2048]
    unsigned short* W2t    = (unsigned short*)(ws + 8785920);    // bf16 [512][512]
    unsigned short* Wf1t   = (unsigned short*)(ws + 8916992);    // bf16 [2048][512]
    unsigned short* Wf2t   = (unsigned short*)(ws + 9441280);    // bf16 [512][2048]
    float*          h2     = ws + 9965568;                       // f32 [2048][512]
    float*          fb     = ws + 11014144;                      // f32 [2048][512]
    float*          outp   = (float*)d_out;

    const int M = BB * NN;  // 2048

    // 1) prep: weights, x, bqkv, biasMs
    prep_kernel<<<dim3(2048, 1, 10), dim3(256), 0, stream>>>(
        x, Wq, Wk, Wv, W1, W2, Wf1, Wf2, bq, bk, bv,
        attn_bias, mask, dist, dist_bar,
        xb, Wqkvt, W1t, W2t, Wf1t, Wf2t, bqkv, biasMs);

    // 2) fused QKV; v written transposed into vT
    mfma_gemm512<0, 1><<<dim3(12, 16), dim3(512), 0, stream>>>(
        xb, Wqkvt, bqkv, qkvb, vT, M, 1536, DD);

    // 3) 4-scale MFMA attention -> bf16 msgT (scrambled W1-input layout)
    attn_kernel<<<dim3(4, HH, BB), dim3(256), 0, stream>>>(qkvb, vT, biasMs, msgT);

    // 4) h1 = silu(msgT @ W1 + b1)
    mfma_gemm64<1, 0><<<dim3(8, 32), dim3(256), 0, stream>>>(
        msgT, W1t, b1, h1, nullptr, M, DD, 2048);

    // 5) h2 = h1 @ W2 + b2 (fp32 out)
    mfma_gemm64<0, 1><<<dim3(8, 32), dim3(256), 0, stream>>>(
        h1, W2t, b2, nullptr, h2, M, DD, DD);

    // 6) y = LN(h2 + x)  (per-wave, barrier-free)
    ln_kernel<1><<<dim3(512), dim3(256), 0, stream>>>(h2, x, g1, be1, yb, yb16);

    // 7) g3 = gelu(y @ Wf1 + bf1)
    mfma_gemm512<2, 0><<<dim3(16, 16), dim3(512), 0, stream>>>(
        yb16, Wf1t, bf1, g3, nullptr, M, FFN_, DD);

    // 8) f = g3 @ Wf2 + bf2 (fp32 out)
    mfma_gemm64<0, 1><<<dim3(8, 32), dim3(256), 0, stream>>>(
        g3, Wf2t, bf2, nullptr, fb, M, DD, 2048);

    // 9) out = LN(f + y)
    ln_kernel<0><<<dim3(512), dim3(256), 0, stream>>>(fb, yb, g2, be2, outp, nullptr);
}